// Round 7
// baseline (376.719 us; speedup 1.0000x reference)
//
#include <hip/hip_runtime.h>
#include <stdint.h>

#define NSPACE 197
#define TFRAMES 8
#define NH 12
#define DIM 768
#define HD 64
#define BATCH 8
#define NQ 1576
#define NK 1576
#define M_REAL 12608   // BATCH*NQ
#define M_PAD 12672    // 99*128
#define VT_LD 1600     // NK padded so OOB key reads stay in-row

typedef __attribute__((ext_vector_type(8))) short s16x8;
typedef __attribute__((ext_vector_type(4))) short s16x4;
typedef __attribute__((ext_vector_type(4))) float f32x4;

__device__ inline uint16_t f2bf(float f) {
    union { float f; uint32_t i; } c; c.f = f;
    uint32_t r = c.i + 0x7FFF + ((c.i >> 16) & 1);
    return (uint16_t)(r >> 16);
}

// single-instruction pack of 2 fp32 -> 2 bf16 (low=lo, high=hi), RNE
__device__ inline uint32_t cvtpk_bf16(float lo, float hi) {
    uint32_t r;
    asm("v_cvt_pk_bf16_f32 %0, %1, %2" : "=v"(r) : "v"(lo), "v"(hi));
    return r;
}

// raw v_exp_f32: exp2 without the OCML denormal-range wrapper.
__device__ inline float exp2_raw(float x) { return __builtin_amdgcn_exp2f(x); }

// async global->LDS, 16B per lane; LDS dest must be wave-uniform base (+lane*16 implicit)
__device__ inline void gld_lds16(const uint16_t* g, uint16_t* l) {
    __builtin_amdgcn_global_load_lds(
        (const __attribute__((address_space(1))) void*)g,
        (__attribute__((address_space(3))) void*)l,
        16, 0, 0);
}

// ---------------- prep: fill_x + fill_s + conv(q_w) + conv(kv_w) ----------------
#define FILLB 4752            // M_PAD*(DIM/8)/256
#define CONVQ_B 288           // DIM*DIM/8/256
#define CONVKV_B 576          // 2*DIM*DIM/8/256
__global__ void prep(const float* __restrict__ t_x, const float* __restrict__ s_x,
                     const float* __restrict__ pos,
                     const float* __restrict__ q_w, const float* __restrict__ kv_w,
                     uint16_t* __restrict__ x_pad, uint16_t* __restrict__ s_pad,
                     uint16_t* __restrict__ wq, uint16_t* __restrict__ wkv) {
    int bx = blockIdx.x, tid = threadIdx.x;
    if (bx < FILLB) {
        int chunk = bx * 256 + tid;
        size_t off = (size_t)chunk * 8;
        s16x8 o;
        if (off < (size_t)M_REAL * DIM) {
            float4 a = *(const float4*)(t_x + off);
            float4 b = *(const float4*)(t_x + off + 4);
            union { s16x8 v; uint32_t u[4]; } p;
            p.u[0] = cvtpk_bf16(a.x, a.y);
            p.u[1] = cvtpk_bf16(a.z, a.w);
            p.u[2] = cvtpk_bf16(b.x, b.y);
            p.u[3] = cvtpk_bf16(b.z, b.w);
            o = p.v;
        } else {
            for (int j = 0; j < 8; j++) o[j] = 0;
        }
        *(s16x8*)(x_pad + off) = o;
    } else if (bx < 2 * FILLB) {
        int chunk = (bx - FILLB) * 256 + tid;
        int i = chunk / (DIM / 8);
        int cc = chunk - i * (DIM / 8);
        int d0 = cc * 8;
        uint16_t* dst = s_pad + (size_t)i * DIM + d0;
        if (i >= M_REAL) {
            s16x8 z; for (int j = 0; j < 8; j++) z[j] = 0;
            *(s16x8*)dst = z;
            return;
        }
        int b = i / NK, rr = i - b * NK;
        int t_i = rr / NSPACE, n_i = rr - t_i * NSPACE;
        const float* src = s_x + ((size_t)(n_i * (BATCH * TFRAMES) + b * TFRAMES + t_i)) * DIM + d0;
        const float* ps = pos + (size_t)rr * DIM + d0;
        float4 a0 = *(const float4*)src;
        float4 a1 = *(const float4*)(src + 4);
        float4 p0 = *(const float4*)ps;
        float4 p1 = *(const float4*)(ps + 4);
        union { s16x8 v; uint32_t u[4]; } o;
        o.u[0] = cvtpk_bf16(a0.x + p0.x, a0.y + p0.y);
        o.u[1] = cvtpk_bf16(a0.z + p0.z, a0.w + p0.w);
        o.u[2] = cvtpk_bf16(a1.x + p1.x, a1.y + p1.y);
        o.u[3] = cvtpk_bf16(a1.z + p1.z, a1.w + p1.w);
        *(s16x8*)dst = o.v;
    } else if (bx < 2 * FILLB + CONVQ_B) {
        int chunk = (bx - 2 * FILLB) * 256 + tid;
        size_t off = (size_t)chunk * 8;
        float4 a = *(const float4*)(q_w + off);
        float4 b = *(const float4*)(q_w + off + 4);
        union { s16x8 v; uint32_t u[4]; } o;
        o.u[0] = cvtpk_bf16(a.x, a.y);
        o.u[1] = cvtpk_bf16(a.z, a.w);
        o.u[2] = cvtpk_bf16(b.x, b.y);
        o.u[3] = cvtpk_bf16(b.z, b.w);
        *(s16x8*)(wq + off) = o.v;
    } else {
        int chunk = (bx - 2 * FILLB - CONVQ_B) * 256 + tid;
        size_t off = (size_t)chunk * 8;
        float4 a = *(const float4*)(kv_w + off);
        float4 b = *(const float4*)(kv_w + off + 4);
        union { s16x8 v; uint32_t u[4]; } o;
        o.u[0] = cvtpk_bf16(a.x, a.y);
        o.u[1] = cvtpk_bf16(a.z, a.w);
        o.u[2] = cvtpk_bf16(b.x, b.y);
        o.u[3] = cvtpk_bf16(b.z, b.w);
        *(s16x8*)(wkv + off) = o.v;
    }
}

__global__ void conv_f2b(const float* __restrict__ src, uint16_t* __restrict__ dst, int n8) {
    int chunk = blockIdx.x * 256 + threadIdx.x;
    if (chunk >= n8) return;
    size_t off = (size_t)chunk * 8;
    float4 a = *(const float4*)(src + off);
    float4 b = *(const float4*)(src + off + 4);
    union { s16x8 v; uint32_t u[4]; } o;
    o.u[0] = cvtpk_bf16(a.x, a.y);
    o.u[1] = cvtpk_bf16(a.z, a.w);
    o.u[2] = cvtpk_bf16(b.x, b.y);
    o.u[3] = cvtpk_bf16(b.z, b.w);
    *(s16x8*)(dst + off) = o.v;
}

// ---------------- GEMM: C = A @ W^T + bias, BK=64 swizzled staging ----------------
// 12 K-iters (vs 24 at BK=32): 32 MFMA per barrier-pair, 2x amortization of the
// vmcnt(0)+barrier drain. LDS [128][64] shorts, linear dest; physical chunk p of
// row R holds global chunk p^(R&7) (pre-swizzled SOURCE address + same XOR on the
// ds_read -> stride-128B fragment reads are bank-conflict-free; rule-21 both-sides).
// MODE 0: Q -> q_buf scaled; MODE 1: KV -> k_buf + v_buf; MODE 2: proj -> fp32 out
template <int MODE>
__global__ __launch_bounds__(256)
void gemm_bt(const uint16_t* __restrict__ A, const uint16_t* __restrict__ W,
             const float* __restrict__ bias,
             uint16_t* __restrict__ out0, uint16_t* __restrict__ out1,
             float* __restrict__ outf) {
    __shared__ uint16_t As[128 * 64];
    __shared__ uint16_t Bs[128 * 64];
    const int t = threadIdx.x;
    const int lane = t & 63, w = t >> 6;
    const int r16 = lane & 15, quad = lane >> 4;
    const int wm = w >> 1, wn = w & 1;
    const int m0 = blockIdx.y * 128;
    const int n0 = blockIdx.x * 128;

    // staging: issue i covers rows i*32..i*32+31; wave w rows w*8..+7 within issue;
    // lane l -> row l>>3, phys chunk l&7, global chunk (l&7)^(l>>3)
    const int arow = lane >> 3;
    const int achk = (lane & 7) ^ arow;
    const uint16_t* Ag = A + (size_t)(m0 + w * 8 + arow) * DIM + achk * 8;
    const uint16_t* Wg = W + (size_t)(n0 + w * 8 + arow) * DIM + achk * 8;
    const int lb = (w * 8) * 64;   // wave-uniform LDS base (shorts)

    f32x4 acc[4][4];
    for (int a = 0; a < 4; a++)
        for (int bb = 0; bb < 4; bb++)
            for (int r = 0; r < 4; r++) acc[a][bb][r] = 0.f;

    for (int kk = 0; kk < DIM; kk += 64) {
        #pragma unroll
        for (int i = 0; i < 4; i++) {
            gld_lds16(Ag + kk + (size_t)(i * 32) * DIM, &As[lb + i * 32 * 64]);
            gld_lds16(Wg + kk + (size_t)(i * 32) * DIM, &Bs[lb + i * 32 * 64]);
        }
        __syncthreads();
        #pragma unroll
        for (int hh = 0; hh < 2; hh++) {
            const int pc = ((hh * 4 + quad) ^ (r16 & 7)) * 8;
            s16x8 af[4], bfr[4];
            #pragma unroll
            for (int mt = 0; mt < 4; mt++)
                af[mt] = *(const s16x8*)&As[(wm * 64 + mt * 16 + r16) * 64 + pc];
            #pragma unroll
            for (int nt = 0; nt < 4; nt++)
                bfr[nt] = *(const s16x8*)&Bs[(wn * 64 + nt * 16 + r16) * 64 + pc];
            #pragma unroll
            for (int mt = 0; mt < 4; mt++)
                #pragma unroll
                for (int nt = 0; nt < 4; nt++)
                    acc[mt][nt] = __builtin_amdgcn_mfma_f32_16x16x32_bf16(af[mt], bfr[nt], acc[mt][nt], 0, 0, 0);
        }
        __syncthreads();
    }

    for (int mt = 0; mt < 4; mt++)
        for (int nt = 0; nt < 4; nt++) {
            int col = n0 + wn * 64 + nt * 16 + r16;
            float bz = bias[col];
            int rowb = m0 + wm * 64 + mt * 16 + quad * 4;
            for (int r = 0; r < 4; r++) {
                int i = rowb + r;
                if (i >= M_REAL) continue;
                float v = acc[mt][nt][r] + bz;
                if (MODE == 0) {
                    int b = i / NQ, nq = i - b * NQ;
                    int h = col >> 6, d = col & 63;
                    out0[(size_t)(((b * NH + h) * NQ) + nq) * HD + d] = f2bf(v * 0.18033688011112042f);
                } else if (MODE == 1) {
                    int b = i / NK, nk = i - b * NK;
                    if (col < DIM) {
                        int h = col >> 6, d = col & 63;
                        out0[(size_t)(((b * NH + h) * NK) + nk) * HD + d] = f2bf(v);
                    } else {
                        int c2 = col - DIM;
                        int h = c2 >> 6, d = c2 & 63;
                        out1[(size_t)(((b * NH + h) * NK) + nk) * HD + d] = f2bf(v);
                    }
                } else {
                    outf[(size_t)i * DIM + col] = v;
                }
            }
        }
}

// ---------------- V transpose: (b,h,nk,64) -> (b,h,64,VT_LD) ----------------
__global__ __launch_bounds__(256)
void transpose_v(const uint16_t* __restrict__ v, uint16_t* __restrict__ vt) {
    __shared__ uint16_t T[64 * 72];
    int tile = blockIdx.x, bh = blockIdx.y;
    int nk0 = tile * 64;
    const uint16_t* V = v + (size_t)bh * NK * HD;
    uint16_t* VT = vt + (size_t)bh * HD * VT_LD;
    int tid = threadIdx.x;
    int rr = tid >> 3;
    int c8 = (tid & 7) * 8;
    for (int p = 0; p < 2; p++) {
        int lr = p * 32 + rr;
        int nk = nk0 + lr;
        s16x8 val;
        if (nk < NK) val = *(const s16x8*)(V + (size_t)nk * HD + c8);
        else for (int j = 0; j < 8; j++) val[j] = 0;
        for (int j = 0; j < 8; j++)
            T[(c8 + j) * 72 + lr] = (uint16_t)val[j];
    }
    __syncthreads();
    for (int p = 0; p < 2; p++) {
        int d = p * 32 + rr;
        s16x8 o = *(const s16x8*)&T[d * 72 + c8];
        *(s16x8*)(VT + (size_t)d * VT_LD + nk0 + c8) = o;
    }
}

// ---------------- flash attention v8: v6 (verified 97.2us) + XCD-chunked block
// swizzle ----------------
// Grid flattened to 1248 = 8 XCDs x 156 works; wgid%8 selects XCD (HW round-robin),
// work = xcd*156 + wgid/8 -> all 13 q-blocks of one (b,h) land on ONE XCD so its
// private L2 serves the shared 400KB K/VT (was: 13 different XCDs -> 165MB FETCH,
// 2.8x re-fetch from HBM on the serial per-iter chain).
#define NITER 50
#define FLASH_WG 1248   // 13 * NH * BATCH
__global__ __launch_bounds__(256)
void flash_attn(const uint16_t* __restrict__ q_buf, const uint16_t* __restrict__ k_buf,
                const uint16_t* __restrict__ vt_buf, uint16_t* __restrict__ ao) {
    __shared__ uint16_t Kb[2][32 * 72];
    __shared__ uint16_t Vb[2][64 * 40];
    // XCD-chunked bijective remap (1248 = 8*156 exactly)
    int wgid = blockIdx.x;
    int work = (wgid & 7) * (FLASH_WG / 8) + (wgid >> 3);
    int qb = work % 13;
    int hb = work / 13;
    int h = hb % NH;
    int b = hb / NH;
    int tid = threadIdx.x;
    int lane = tid & 63, w = tid >> 6;
    int r16 = lane & 15, quad = lane >> 4;
    size_t bh = (size_t)(b * NH + h);
    const uint16_t* Q = q_buf + bh * NQ * HD;
    const uint16_t* K = k_buf + bh * NK * HD;
    const uint16_t* VT = vt_buf + bh * HD * VT_LD;
    int q0 = qb * 128 + w * 32;

    const int kg = tid >> 3;
    const int kc = (tid & 7) * 8;
    const int kslot = ((kg >> 3) << 2) + (kg & 3) + ((kg & 4) ? 16 : 0);
    const int vd = tid >> 2;
    const int vc = (tid & 3) * 8;
    const uint16_t* Kg = K + (size_t)kg * HD + kc;
    const uint16_t* Vg = VT + (size_t)vd * VT_LD + vc;
    uint16_t* Kw = &Kb[0][kslot * 72 + kc];
    uint16_t* Vw = &Vb[0][vd * 40 + vc];
    const int KBSZ = 32 * 72, VBSZ = 64 * 40;

    s16x8 qf[2][2];
    for (int m = 0; m < 2; m++) {
        int qrow = q0 + m * 16 + r16;
        if (qrow < NQ) {
            qf[m][0] = *(const s16x8*)(Q + (size_t)qrow * HD + quad * 8);
            qf[m][1] = *(const s16x8*)(Q + (size_t)qrow * HD + 32 + quad * 8);
        } else {
            for (int j = 0; j < 8; j++) { qf[m][0][j] = 0; qf[m][1][j] = 0; }
        }
    }

    f32x4 z4;
    for (int r = 0; r < 4; r++) z4[r] = 0.f;

    f32x4 oT[2][4];
    f32x4 lsum4[2];
    for (int m = 0; m < 2; m++) {
        for (int dt = 0; dt < 4; dt++)
            for (int r = 0; r < 4; r++) oT[m][dt][r] = 0.f;
        for (int r = 0; r < 4; r++) lsum4[m][r] = 0.f;
    }

    {
        s16x8 kv = *(const s16x8*)Kg;
        s16x8 vv = *(const s16x8*)Vg;
        *(s16x8*)Kw = kv;
        *(s16x8*)Vw = vv;
    }
    __syncthreads();

    for (int it = 0; it < NITER - 1; it++) {
        int kb = it * 32;
        int cur = it & 1, nxt = cur ^ 1;
        s16x8 knv = *(const s16x8*)(Kg + (size_t)(kb + 32) * HD);
        s16x8 vnv = *(const s16x8*)(Vg + kb + 32);

        const uint16_t* Kc = &Kb[cur][0];
        const uint16_t* Vc = &Vb[cur][0];
        s16x8 kfA0 = *(const s16x8*)(Kc + r16 * 72 + quad * 8);
        s16x8 kfA1 = *(const s16x8*)(Kc + r16 * 72 + 32 + quad * 8);
        s16x8 kfB0 = *(const s16x8*)(Kc + (16 + r16) * 72 + quad * 8);
        s16x8 kfB1 = *(const s16x8*)(Kc + (16 + r16) * 72 + 32 + quad * 8);

        s16x8 pf[2];
        #pragma unroll
        for (int m = 0; m < 2; m++) {
            f32x4 sA = __builtin_amdgcn_mfma_f32_16x16x32_bf16(kfA0, qf[m][0], z4, 0, 0, 0);
            sA = __builtin_amdgcn_mfma_f32_16x16x32_bf16(kfA1, qf[m][1], sA, 0, 0, 0);
            f32x4 sB = __builtin_amdgcn_mfma_f32_16x16x32_bf16(kfB0, qf[m][0], z4, 0, 0, 0);
            sB = __builtin_amdgcn_mfma_f32_16x16x32_bf16(kfB1, qf[m][1], sB, 0, 0, 0);
            f32x4 pA, pB;
            #pragma unroll
            for (int r = 0; r < 4; r++) { pA[r] = exp2_raw(sA[r]); pB[r] = exp2_raw(sB[r]); }
            lsum4[m] += pA;
            lsum4[m] += pB;
            union { s16x8 v; uint32_t u[4]; } pk;
            pk.u[0] = cvtpk_bf16(pA[0], pA[1]);
            pk.u[1] = cvtpk_bf16(pA[2], pA[3]);
            pk.u[2] = cvtpk_bf16(pB[0], pB[1]);
            pk.u[3] = cvtpk_bf16(pB[2], pB[3]);
            pf[m] = pk.v;
        }
        #pragma unroll
        for (int dt = 0; dt < 4; dt++) {
            s16x8 vf = *(const s16x8*)(Vc + (dt * 16 + r16) * 40 + quad * 8);
            oT[0][dt] = __builtin_amdgcn_mfma_f32_16x16x32_bf16(vf, pf[0], oT[0][dt], 0, 0, 0);
            oT[1][dt] = __builtin_amdgcn_mfma_f32_16x16x32_bf16(vf, pf[1], oT[1][dt], 0, 0, 0);
        }
        *(s16x8*)(Kw + nxt * KBSZ) = knv;
        *(s16x8*)(Vw + nxt * VBSZ) = vnv;
        __syncthreads();
    }

    {
        const int it = NITER - 1;
        const int kb = it * 32;
        const int cur = it & 1;
        const uint16_t* Kc = &Kb[cur][0];
        const uint16_t* Vc = &Vb[cur][0];
        s16x8 kfA0 = *(const s16x8*)(Kc + r16 * 72 + quad * 8);
        s16x8 kfA1 = *(const s16x8*)(Kc + r16 * 72 + 32 + quad * 8);
        s16x8 kfB0 = *(const s16x8*)(Kc + (16 + r16) * 72 + quad * 8);
        s16x8 kfB1 = *(const s16x8*)(Kc + (16 + r16) * 72 + 32 + quad * 8);

        s16x8 pf[2];
        #pragma unroll
        for (int m = 0; m < 2; m++) {
            f32x4 sA = __builtin_amdgcn_mfma_f32_16x16x32_bf16(kfA0, qf[m][0], z4, 0, 0, 0);
            sA = __builtin_amdgcn_mfma_f32_16x16x32_bf16(kfA1, qf[m][1], sA, 0, 0, 0);
            f32x4 sB = __builtin_amdgcn_mfma_f32_16x16x32_bf16(kfB0, qf[m][0], z4, 0, 0, 0);
            sB = __builtin_amdgcn_mfma_f32_16x16x32_bf16(kfB1, qf[m][1], sB, 0, 0, 0);
            f32x4 pA, pB;
            #pragma unroll
            for (int r = 0; r < 4; r++) {
                pA[r] = (kb + quad * 8 + r < NK)     ? exp2_raw(sA[r]) : 0.f;
                pB[r] = (kb + quad * 8 + 4 + r < NK) ? exp2_raw(sB[r]) : 0.f;
            }
            lsum4[m] += pA;
            lsum4[m] += pB;
            union { s16x8 v; uint32_t u[4]; } pk;
            pk.u[0] = cvtpk_bf16(pA[0], pA[1]);
            pk.u[1] = cvtpk_bf16(pA[2], pA[3]);
            pk.u[2] = cvtpk_bf16(pB[0], pB[1]);
            pk.u[3] = cvtpk_bf16(pB[2], pB[3]);
            pf[m] = pk.v;
        }
        #pragma unroll
        for (int dt = 0; dt < 4; dt++) {
            s16x8 vf = *(const s16x8*)(Vc + (dt * 16 + r16) * 40 + quad * 8);
            oT[0][dt] = __builtin_amdgcn_mfma_f32_16x16x32_bf16(vf, pf[0], oT[0][dt], 0, 0, 0);
            oT[1][dt] = __builtin_amdgcn_mfma_f32_16x16x32_bf16(vf, pf[1], oT[1][dt], 0, 0, 0);
        }
    }

    #pragma unroll
    for (int m = 0; m < 2; m++) {
        float rs = lsum4[m][0] + lsum4[m][1] + lsum4[m][2] + lsum4[m][3];
        rs += __shfl_xor(rs, 16);
        rs += __shfl_xor(rs, 32);
        int q = q0 + m * 16 + r16;
        if (q >= NQ) continue;
        float inv = 1.0f / rs;
        size_t rowoff = (size_t)(b * NQ + q) * DIM + h * HD;
        #pragma unroll
        for (int dt = 0; dt < 4; dt++) {
            union { s16x4 v; uint32_t u[2]; } o;
            o.u[0] = cvtpk_bf16(oT[m][dt][0] * inv, oT[m][dt][1] * inv);
            o.u[1] = cvtpk_bf16(oT[m][dt][2] * inv, oT[m][dt][3] * inv);
            *(s16x4*)(ao + rowoff + dt * 16 + quad * 4) = o.v;
        }
    }
}

// ---------------- launch ----------------
extern "C" void kernel_launch(void* const* d_in, const int* in_sizes, int n_in,
                              void* d_out, int out_size, void* d_ws, size_t ws_size,
                              hipStream_t stream) {
    const float* s_x    = (const float*)d_in[0];
    const float* t_x    = (const float*)d_in[1];
    const float* pos    = (const float*)d_in[2];
    const float* q_w    = (const float*)d_in[3];
    const float* q_b    = (const float*)d_in[4];
    const float* kv_w   = (const float*)d_in[5];
    const float* kv_b   = (const float*)d_in[6];
    const float* proj_w = (const float*)d_in[7];
    const float* proj_b = (const float*)d_in[8];
    float* out = (float*)d_out;

    char* ws = (char*)d_ws;
    size_t off = 0;
    auto carve = [&](size_t bytes) {
        void* p = ws + off;
        off += (bytes + 255) & ~(size_t)255;
        return p;
    };
    uint16_t* x_pad   = (uint16_t*)carve((size_t)M_PAD * DIM * 2);
    uint16_t* s_pad   = (uint16_t*)carve((size_t)M_PAD * DIM * 2);
    uint16_t* q_buf   = (uint16_t*)carve((size_t)BATCH * NH * NQ * HD * 2);
    uint16_t* k_buf   = (uint16_t*)carve((size_t)BATCH * NH * NK * HD * 2);
    uint16_t* vt_buf  = (uint16_t*)carve((size_t)BATCH * NH * HD * VT_LD * 2);
    uint16_t* wq_buf  = (uint16_t*)carve((size_t)DIM * DIM * 2);
    uint16_t* wkv_buf = (uint16_t*)carve((size_t)2 * DIM * DIM * 2);
    if (off > ws_size) return;
    uint16_t* v_buf = x_pad;   // x_pad dead after Q GEMM (V fills rows < M_REAL; tail stays 0)
    uint16_t* ao    = x_pad;   // v_buf dead after transpose
    uint16_t* wproj = wq_buf;  // wq dead after Q GEMM

    const int wq8 = DIM * DIM / 8;
    const int prep_blocks = 2 * FILLB + CONVQ_B + CONVKV_B;

    prep<<<prep_blocks, 256, 0, stream>>>(t_x, s_x, pos, q_w, kv_w,
                                          x_pad, s_pad, wq_buf, wkv_buf);

    gemm_bt<0><<<dim3(DIM / 128, M_PAD / 128), 256, 0, stream>>>(x_pad, wq_buf, q_b, q_buf, nullptr, nullptr);
    gemm_bt<1><<<dim3(2 * DIM / 128, M_PAD / 128), 256, 0, stream>>>(s_pad, wkv_buf, kv_b, k_buf, v_buf, nullptr);
    transpose_v<<<dim3(VT_LD / 64, BATCH * NH), 256, 0, stream>>>(v_buf, vt_buf);

    conv_f2b<<<(wq8 + 255) / 256, 256, 0, stream>>>(proj_w, wproj, wq8);

    flash_attn<<<FLASH_WG, 256, 0, stream>>>(q_buf, k_buf, vt_buf, ao);

    gemm_bt<2><<<dim3(DIM / 128, M_PAD / 128), 256, 0, stream>>>(ao, wproj, proj_b, nullptr, nullptr, out);
}

// Round 8
// 369.233 us; speedup vs baseline: 1.0203x; 1.0203x over previous
//
#include <hip/hip_runtime.h>
#include <stdint.h>

#define NSPACE 197
#define TFRAMES 8
#define NH 12
#define DIM 768
#define HD 64
#define BATCH 8
#define NQ 1576
#define NK 1576
#define M_REAL 12608   // BATCH*NQ
#define M_PAD 12672    // 99*128
#define VT_LD 1600     // NK padded so OOB key reads stay in-row

typedef __attribute__((ext_vector_type(8))) short s16x8;
typedef __attribute__((ext_vector_type(4))) short s16x4;
typedef __attribute__((ext_vector_type(4))) float f32x4;

__device__ inline uint16_t f2bf(float f) {
    union { float f; uint32_t i; } c; c.f = f;
    uint32_t r = c.i + 0x7FFF + ((c.i >> 16) & 1);
    return (uint16_t)(r >> 16);
}

// single-instruction pack of 2 fp32 -> 2 bf16 (low=lo, high=hi), RNE
__device__ inline uint32_t cvtpk_bf16(float lo, float hi) {
    uint32_t r;
    asm("v_cvt_pk_bf16_f32 %0, %1, %2" : "=v"(r) : "v"(lo), "v"(hi));
    return r;
}

// raw v_exp_f32: exp2 without the OCML denormal-range wrapper.
__device__ inline float exp2_raw(float x) { return __builtin_amdgcn_exp2f(x); }

// async global->LDS, 16B per lane; LDS dest must be wave-uniform base (+lane*16 implicit)
__device__ inline void gld_lds16(const uint16_t* g, uint16_t* l) {
    __builtin_amdgcn_global_load_lds(
        (const __attribute__((address_space(1))) void*)g,
        (__attribute__((address_space(3))) void*)l,
        16, 0, 0);
}

// ---------------- prep: fill_x + fill_s + conv(q_w) + conv(kv_w) ----------------
#define FILLB 4752            // M_PAD*(DIM/8)/256
#define CONVQ_B 288           // DIM*DIM/8/256
#define CONVKV_B 576          // 2*DIM*DIM/8/256
__global__ void prep(const float* __restrict__ t_x, const float* __restrict__ s_x,
                     const float* __restrict__ pos,
                     const float* __restrict__ q_w, const float* __restrict__ kv_w,
                     uint16_t* __restrict__ x_pad, uint16_t* __restrict__ s_pad,
                     uint16_t* __restrict__ wq, uint16_t* __restrict__ wkv) {
    int bx = blockIdx.x, tid = threadIdx.x;
    if (bx < FILLB) {
        int chunk = bx * 256 + tid;
        size_t off = (size_t)chunk * 8;
        s16x8 o;
        if (off < (size_t)M_REAL * DIM) {
            float4 a = *(const float4*)(t_x + off);
            float4 b = *(const float4*)(t_x + off + 4);
            union { s16x8 v; uint32_t u[4]; } p;
            p.u[0] = cvtpk_bf16(a.x, a.y);
            p.u[1] = cvtpk_bf16(a.z, a.w);
            p.u[2] = cvtpk_bf16(b.x, b.y);
            p.u[3] = cvtpk_bf16(b.z, b.w);
            o = p.v;
        } else {
            for (int j = 0; j < 8; j++) o[j] = 0;
        }
        *(s16x8*)(x_pad + off) = o;
    } else if (bx < 2 * FILLB) {
        int chunk = (bx - FILLB) * 256 + tid;
        int i = chunk / (DIM / 8);
        int cc = chunk - i * (DIM / 8);
        int d0 = cc * 8;
        uint16_t* dst = s_pad + (size_t)i * DIM + d0;
        if (i >= M_REAL) {
            s16x8 z; for (int j = 0; j < 8; j++) z[j] = 0;
            *(s16x8*)dst = z;
            return;
        }
        int b = i / NK, rr = i - b * NK;
        int t_i = rr / NSPACE, n_i = rr - t_i * NSPACE;
        const float* src = s_x + ((size_t)(n_i * (BATCH * TFRAMES) + b * TFRAMES + t_i)) * DIM + d0;
        const float* ps = pos + (size_t)rr * DIM + d0;
        float4 a0 = *(const float4*)src;
        float4 a1 = *(const float4*)(src + 4);
        float4 p0 = *(const float4*)ps;
        float4 p1 = *(const float4*)(ps + 4);
        union { s16x8 v; uint32_t u[4]; } o;
        o.u[0] = cvtpk_bf16(a0.x + p0.x, a0.y + p0.y);
        o.u[1] = cvtpk_bf16(a0.z + p0.z, a0.w + p0.w);
        o.u[2] = cvtpk_bf16(a1.x + p1.x, a1.y + p1.y);
        o.u[3] = cvtpk_bf16(a1.z + p1.z, a1.w + p1.w);
        *(s16x8*)dst = o.v;
    } else if (bx < 2 * FILLB + CONVQ_B) {
        int chunk = (bx - 2 * FILLB) * 256 + tid;
        size_t off = (size_t)chunk * 8;
        float4 a = *(const float4*)(q_w + off);
        float4 b = *(const float4*)(q_w + off + 4);
        union { s16x8 v; uint32_t u[4]; } o;
        o.u[0] = cvtpk_bf16(a.x, a.y);
        o.u[1] = cvtpk_bf16(a.z, a.w);
        o.u[2] = cvtpk_bf16(b.x, b.y);
        o.u[3] = cvtpk_bf16(b.z, b.w);
        *(s16x8*)(wq + off) = o.v;
    } else {
        int chunk = (bx - 2 * FILLB - CONVQ_B) * 256 + tid;
        size_t off = (size_t)chunk * 8;
        float4 a = *(const float4*)(kv_w + off);
        float4 b = *(const float4*)(kv_w + off + 4);
        union { s16x8 v; uint32_t u[4]; } o;
        o.u[0] = cvtpk_bf16(a.x, a.y);
        o.u[1] = cvtpk_bf16(a.z, a.w);
        o.u[2] = cvtpk_bf16(b.x, b.y);
        o.u[3] = cvtpk_bf16(b.z, b.w);
        *(s16x8*)(wkv + off) = o.v;
    }
}

__global__ void conv_f2b(const float* __restrict__ src, uint16_t* __restrict__ dst, int n8) {
    int chunk = blockIdx.x * 256 + threadIdx.x;
    if (chunk >= n8) return;
    size_t off = (size_t)chunk * 8;
    float4 a = *(const float4*)(src + off);
    float4 b = *(const float4*)(src + off + 4);
    union { s16x8 v; uint32_t u[4]; } o;
    o.u[0] = cvtpk_bf16(a.x, a.y);
    o.u[1] = cvtpk_bf16(a.z, a.w);
    o.u[2] = cvtpk_bf16(b.x, b.y);
    o.u[3] = cvtpk_bf16(b.z, b.w);
    *(s16x8*)(dst + off) = o.v;
}

// ---------------- GEMM (round-2 verified, BK=32 linear): C = A @ W^T + bias ------
// MODE 0: Q -> q_buf scaled; MODE 1: KV -> k_buf + v_buf; MODE 2: proj -> fp32 out
template <int MODE>
__global__ __launch_bounds__(256)
void gemm_bt(const uint16_t* __restrict__ A, const uint16_t* __restrict__ W,
             const float* __restrict__ bias,
             uint16_t* __restrict__ out0, uint16_t* __restrict__ out1,
             float* __restrict__ outf) {
    __shared__ uint16_t As[128 * 32];
    __shared__ uint16_t Bs[128 * 32];
    const int t = threadIdx.x;
    const int lane = t & 63, w = t >> 6;
    const int r16 = lane & 15, quad = lane >> 4;
    const int wm = w >> 1, wn = w & 1;
    const int m0 = blockIdx.y * 128;
    const int n0 = blockIdx.x * 128;

    const int srow = w * 32 + (lane >> 2);
    const int scol = (lane & 3) * 8;
    const uint16_t* Ag = A + (size_t)(m0 + srow) * DIM + scol;
    const uint16_t* Wg = W + (size_t)(n0 + srow) * DIM + scol;
    uint16_t* Asw = &As[w * 32 * 32];
    uint16_t* Bsw = &Bs[w * 32 * 32];

    f32x4 acc[4][4];
    for (int a = 0; a < 4; a++)
        for (int bb = 0; bb < 4; bb++)
            for (int r = 0; r < 4; r++) acc[a][bb][r] = 0.f;

    for (int kk = 0; kk < DIM; kk += 32) {
        gld_lds16(Ag + kk, Asw);
        gld_lds16(Ag + kk + (size_t)16 * DIM, Asw + 16 * 32);
        gld_lds16(Wg + kk, Bsw);
        gld_lds16(Wg + kk + (size_t)16 * DIM, Bsw + 16 * 32);
        __syncthreads();
        s16x8 af[4], bfr[4];
        for (int mt = 0; mt < 4; mt++)
            af[mt] = *(const s16x8*)&As[(wm * 64 + mt * 16 + r16) * 32 + quad * 8];
        for (int nt = 0; nt < 4; nt++)
            bfr[nt] = *(const s16x8*)&Bs[(wn * 64 + nt * 16 + r16) * 32 + quad * 8];
        for (int mt = 0; mt < 4; mt++)
            for (int nt = 0; nt < 4; nt++)
                acc[mt][nt] = __builtin_amdgcn_mfma_f32_16x16x32_bf16(af[mt], bfr[nt], acc[mt][nt], 0, 0, 0);
        __syncthreads();
    }

    for (int mt = 0; mt < 4; mt++)
        for (int nt = 0; nt < 4; nt++) {
            int col = n0 + wn * 64 + nt * 16 + r16;
            float bz = bias[col];
            int rowb = m0 + wm * 64 + mt * 16 + quad * 4;
            for (int r = 0; r < 4; r++) {
                int i = rowb + r;
                if (i >= M_REAL) continue;
                float v = acc[mt][nt][r] + bz;
                if (MODE == 0) {
                    int b = i / NQ, nq = i - b * NQ;
                    int h = col >> 6, d = col & 63;
                    out0[(size_t)(((b * NH + h) * NQ) + nq) * HD + d] = f2bf(v * 0.18033688011112042f);
                } else if (MODE == 1) {
                    int b = i / NK, nk = i - b * NK;
                    if (col < DIM) {
                        int h = col >> 6, d = col & 63;
                        out0[(size_t)(((b * NH + h) * NK) + nk) * HD + d] = f2bf(v);
                    } else {
                        int c2 = col - DIM;
                        int h = c2 >> 6, d = c2 & 63;
                        out1[(size_t)(((b * NH + h) * NK) + nk) * HD + d] = f2bf(v);
                    }
                } else {
                    outf[(size_t)i * DIM + col] = v;
                }
            }
        }
}

// ---------------- V transpose: (b,h,nk,64) -> (b,h,64,VT_LD) ----------------
__global__ __launch_bounds__(256)
void transpose_v(const uint16_t* __restrict__ v, uint16_t* __restrict__ vt) {
    __shared__ uint16_t T[64 * 72];
    int tile = blockIdx.x, bh = blockIdx.y;
    int nk0 = tile * 64;
    const uint16_t* V = v + (size_t)bh * NK * HD;
    uint16_t* VT = vt + (size_t)bh * HD * VT_LD;
    int tid = threadIdx.x;
    int rr = tid >> 3;
    int c8 = (tid & 7) * 8;
    for (int p = 0; p < 2; p++) {
        int lr = p * 32 + rr;
        int nk = nk0 + lr;
        s16x8 val;
        if (nk < NK) val = *(const s16x8*)(V + (size_t)nk * HD + c8);
        else for (int j = 0; j < 8; j++) val[j] = 0;
        for (int j = 0; j < 8; j++)
            T[(c8 + j) * 72 + lr] = (uint16_t)val[j];
    }
    __syncthreads();
    for (int p = 0; p < 2; p++) {
        int d = p * 32 + rr;
        s16x8 o = *(const s16x8*)&T[d * 72 + c8];
        *(s16x8*)(VT + (size_t)d * VT_LD + nk0 + c8) = o;
    }
}

// ---------------- flash attention v9: QBLK 16/wave (64 q/wg) for 2x grid ----------
// Grid 2400 wgs (= 8 XCD x 300 = 12 bh x 25 qb per XCD chunk, bijective). LDS 19456B
// -> exactly 8 wgs/CU; VGPR <= 64 -> 8 waves/SIMD: grid was the occupancy limiter
// (round-7: 31% occ, all throughput floors ~6x below measured dur -> latency-bound).
// Per-iter chain and verified K-slot permutation identical to v8; m-loop removed.
#define NITER 50
#define NQB 25              // ceil(NQ/64)
#define FLASH_WG 2400       // NQB * NH * BATCH
__global__ __launch_bounds__(256)
void flash_attn(const uint16_t* __restrict__ q_buf, const uint16_t* __restrict__ k_buf,
                const uint16_t* __restrict__ vt_buf, uint16_t* __restrict__ ao) {
    __shared__ uint16_t Kb[2][32 * 72];
    __shared__ uint16_t Vb[2][64 * 40];
    // XCD-chunked bijective remap (2400 = 8*300 exactly)
    int wgid = blockIdx.x;
    int work = (wgid & 7) * (FLASH_WG / 8) + (wgid >> 3);
    int qb = work % NQB;
    int hb = work / NQB;
    int h = hb % NH;
    int b = hb / NH;
    int tid = threadIdx.x;
    int lane = tid & 63, w = tid >> 6;
    int r16 = lane & 15, quad = lane >> 4;
    size_t bh = (size_t)(b * NH + h);
    const uint16_t* Q = q_buf + bh * NQ * HD;
    const uint16_t* K = k_buf + bh * NK * HD;
    const uint16_t* VT = vt_buf + bh * HD * VT_LD;
    int q0 = qb * 64 + w * 16;

    const int kg = tid >> 3;
    const int kc = (tid & 7) * 8;
    const int kslot = ((kg >> 3) << 2) + (kg & 3) + ((kg & 4) ? 16 : 0);
    const int vd = tid >> 2;
    const int vc = (tid & 3) * 8;
    const uint16_t* Kg = K + (size_t)kg * HD + kc;
    const uint16_t* Vg = VT + (size_t)vd * VT_LD + vc;
    uint16_t* Kw = &Kb[0][kslot * 72 + kc];
    uint16_t* Vw = &Vb[0][vd * 40 + vc];
    const int KBSZ = 32 * 72, VBSZ = 64 * 40;

    s16x8 qf[2];
    {
        int qrow = q0 + r16;
        if (qrow < NQ) {
            qf[0] = *(const s16x8*)(Q + (size_t)qrow * HD + quad * 8);
            qf[1] = *(const s16x8*)(Q + (size_t)qrow * HD + 32 + quad * 8);
        } else {
            for (int j = 0; j < 8; j++) { qf[0][j] = 0; qf[1][j] = 0; }
        }
    }

    f32x4 z4;
    for (int r = 0; r < 4; r++) z4[r] = 0.f;

    f32x4 oT[4];
    f32x4 lsum4;
    for (int dt = 0; dt < 4; dt++)
        for (int r = 0; r < 4; r++) oT[dt][r] = 0.f;
    for (int r = 0; r < 4; r++) lsum4[r] = 0.f;

    {
        s16x8 kv = *(const s16x8*)Kg;
        s16x8 vv = *(const s16x8*)Vg;
        *(s16x8*)Kw = kv;
        *(s16x8*)Vw = vv;
    }
    __syncthreads();

    for (int it = 0; it < NITER - 1; it++) {
        int kb = it * 32;
        int cur = it & 1, nxt = cur ^ 1;
        s16x8 knv = *(const s16x8*)(Kg + (size_t)(kb + 32) * HD);
        s16x8 vnv = *(const s16x8*)(Vg + kb + 32);

        const uint16_t* Kc = &Kb[cur][0];
        const uint16_t* Vc = &Vb[cur][0];
        s16x8 kfA0 = *(const s16x8*)(Kc + r16 * 72 + quad * 8);
        s16x8 kfA1 = *(const s16x8*)(Kc + r16 * 72 + 32 + quad * 8);
        s16x8 kfB0 = *(const s16x8*)(Kc + (16 + r16) * 72 + quad * 8);
        s16x8 kfB1 = *(const s16x8*)(Kc + (16 + r16) * 72 + 32 + quad * 8);

        f32x4 sA = __builtin_amdgcn_mfma_f32_16x16x32_bf16(kfA0, qf[0], z4, 0, 0, 0);
        sA = __builtin_amdgcn_mfma_f32_16x16x32_bf16(kfA1, qf[1], sA, 0, 0, 0);
        f32x4 sB = __builtin_amdgcn_mfma_f32_16x16x32_bf16(kfB0, qf[0], z4, 0, 0, 0);
        sB = __builtin_amdgcn_mfma_f32_16x16x32_bf16(kfB1, qf[1], sB, 0, 0, 0);
        f32x4 pA, pB;
        #pragma unroll
        for (int r = 0; r < 4; r++) { pA[r] = exp2_raw(sA[r]); pB[r] = exp2_raw(sB[r]); }
        lsum4 += pA;
        lsum4 += pB;
        union { s16x8 v; uint32_t u[4]; } pk;
        pk.u[0] = cvtpk_bf16(pA[0], pA[1]);
        pk.u[1] = cvtpk_bf16(pA[2], pA[3]);
        pk.u[2] = cvtpk_bf16(pB[0], pB[1]);
        pk.u[3] = cvtpk_bf16(pB[2], pB[3]);
        s16x8 pf = pk.v;

        #pragma unroll
        for (int dt = 0; dt < 4; dt++) {
            s16x8 vf = *(const s16x8*)(Vc + (dt * 16 + r16) * 40 + quad * 8);
            oT[dt] = __builtin_amdgcn_mfma_f32_16x16x32_bf16(vf, pf, oT[dt], 0, 0, 0);
        }
        *(s16x8*)(Kw + nxt * KBSZ) = knv;
        *(s16x8*)(Vw + nxt * VBSZ) = vnv;
        __syncthreads();
    }

    {
        const int it = NITER - 1;
        const int kb = it * 32;
        const int cur = it & 1;
        const uint16_t* Kc = &Kb[cur][0];
        const uint16_t* Vc = &Vb[cur][0];
        s16x8 kfA0 = *(const s16x8*)(Kc + r16 * 72 + quad * 8);
        s16x8 kfA1 = *(const s16x8*)(Kc + r16 * 72 + 32 + quad * 8);
        s16x8 kfB0 = *(const s16x8*)(Kc + (16 + r16) * 72 + quad * 8);
        s16x8 kfB1 = *(const s16x8*)(Kc + (16 + r16) * 72 + 32 + quad * 8);

        f32x4 sA = __builtin_amdgcn_mfma_f32_16x16x32_bf16(kfA0, qf[0], z4, 0, 0, 0);
        sA = __builtin_amdgcn_mfma_f32_16x16x32_bf16(kfA1, qf[1], sA, 0, 0, 0);
        f32x4 sB = __builtin_amdgcn_mfma_f32_16x16x32_bf16(kfB0, qf[0], z4, 0, 0, 0);
        sB = __builtin_amdgcn_mfma_f32_16x16x32_bf16(kfB1, qf[1], sB, 0, 0, 0);
        f32x4 pA, pB;
        #pragma unroll
        for (int r = 0; r < 4; r++) {
            pA[r] = (kb + quad * 8 + r < NK)     ? exp2_raw(sA[r]) : 0.f;
            pB[r] = (kb + quad * 8 + 4 + r < NK) ? exp2_raw(sB[r]) : 0.f;
        }
        lsum4 += pA;
        lsum4 += pB;
        union { s16x8 v; uint32_t u[4]; } pk;
        pk.u[0] = cvtpk_bf16(pA[0], pA[1]);
        pk.u[1] = cvtpk_bf16(pA[2], pA[3]);
        pk.u[2] = cvtpk_bf16(pB[0], pB[1]);
        pk.u[3] = cvtpk_bf16(pB[2], pB[3]);
        s16x8 pf = pk.v;

        #pragma unroll
        for (int dt = 0; dt < 4; dt++) {
            s16x8 vf = *(const s16x8*)(Vc + (dt * 16 + r16) * 40 + quad * 8);
            oT[dt] = __builtin_amdgcn_mfma_f32_16x16x32_bf16(vf, pf, oT[dt], 0, 0, 0);
        }
    }

    {
        float rs = lsum4[0] + lsum4[1] + lsum4[2] + lsum4[3];
        rs += __shfl_xor(rs, 16);
        rs += __shfl_xor(rs, 32);
        int q = q0 + r16;
        if (q < NQ) {
            float inv = 1.0f / rs;
            size_t rowoff = (size_t)(b * NQ + q) * DIM + h * HD;
            #pragma unroll
            for (int dt = 0; dt < 4; dt++) {
                union { s16x4 v; uint32_t u[2]; } o;
                o.u[0] = cvtpk_bf16(oT[dt][0] * inv, oT[dt][1] * inv);
                o.u[1] = cvtpk_bf16(oT[dt][2] * inv, oT[dt][3] * inv);
                *(s16x4*)(ao + rowoff + dt * 16 + quad * 4) = o.v;
            }
        }
    }
}

// ---------------- launch ----------------
extern "C" void kernel_launch(void* const* d_in, const int* in_sizes, int n_in,
                              void* d_out, int out_size, void* d_ws, size_t ws_size,
                              hipStream_t stream) {
    const float* s_x    = (const float*)d_in[0];
    const float* t_x    = (const float*)d_in[1];
    const float* pos    = (const float*)d_in[2];
    const float* q_w    = (const float*)d_in[3];
    const float* q_b    = (const float*)d_in[4];
    const float* kv_w   = (const float*)d_in[5];
    const float* kv_b   = (const float*)d_in[6];
    const float* proj_w = (const float*)d_in[7];
    const float* proj_b = (const float*)d_in[8];
    float* out = (float*)d_out;

    char* ws = (char*)d_ws;
    size_t off = 0;
    auto carve = [&](size_t bytes) {
        void* p = ws + off;
        off += (bytes + 255) & ~(size_t)255;
        return p;
    };
    uint16_t* x_pad   = (uint16_t*)carve((size_t)M_PAD * DIM * 2);
    uint16_t* s_pad   = (uint16_t*)carve((size_t)M_PAD * DIM * 2);
    uint16_t* q_buf   = (uint16_t*)carve((size_t)BATCH * NH * NQ * HD * 2);
    uint16_t* k_buf   = (uint16_t*)carve((size_t)BATCH * NH * NK * HD * 2);
    uint16_t* vt_buf  = (uint16_t*)carve((size_t)BATCH * NH * HD * VT_LD * 2);
    uint16_t* wq_buf  = (uint16_t*)carve((size_t)DIM * DIM * 2);
    uint16_t* wkv_buf = (uint16_t*)carve((size_t)2 * DIM * DIM * 2);
    if (off > ws_size) return;
    uint16_t* v_buf = x_pad;   // x_pad dead after Q GEMM
    uint16_t* ao    = x_pad;   // v_buf dead after transpose
    uint16_t* wproj = wq_buf;  // wq dead after Q GEMM

    const int wq8 = DIM * DIM / 8;
    const int prep_blocks = 2 * FILLB + CONVQ_B + CONVKV_B;

    prep<<<prep_blocks, 256, 0, stream>>>(t_x, s_x, pos, q_w, kv_w,
                                          x_pad, s_pad, wq_buf, wkv_buf);

    gemm_bt<0><<<dim3(DIM / 128, M_PAD / 128), 256, 0, stream>>>(x_pad, wq_buf, q_b, q_buf, nullptr, nullptr);
    gemm_bt<1><<<dim3(2 * DIM / 128, M_PAD / 128), 256, 0, stream>>>(s_pad, wkv_buf, kv_b, k_buf, v_buf, nullptr);
    transpose_v<<<dim3(VT_LD / 64, BATCH * NH), 256, 0, stream>>>(v_buf, vt_buf);

    conv_f2b<<<(wq8 + 255) / 256, 256, 0, stream>>>(proj_w, wproj, wq8);

    flash_attn<<<FLASH_WG, 256, 0, stream>>>(q_buf, k_buf, vt_buf, ao);

    gemm_bt<2><<<dim3(DIM / 128, M_PAD / 128), 256, 0, stream>>>(ao, wproj, proj_b, nullptr, nullptr, out);
}

// Round 9
// 356.134 us; speedup vs baseline: 1.0578x; 1.0368x over previous
//
#include <hip/hip_runtime.h>
#include <stdint.h>

#define NSPACE 197
#define TFRAMES 8
#define NH 12
#define DIM 768
#define HD 64
#define BATCH 8
#define NQ 1576
#define NK 1576
#define M_REAL 12608   // BATCH*NQ
#define M_PAD 12672    // 99*128
#define VT_LD 1600     // NK padded so OOB key reads stay in-row

typedef __attribute__((ext_vector_type(8))) short s16x8;
typedef __attribute__((ext_vector_type(4))) short s16x4;
typedef __attribute__((ext_vector_type(4))) float f32x4;

__device__ inline uint16_t f2bf(float f) {
    union { float f; uint32_t i; } c; c.f = f;
    uint32_t r = c.i + 0x7FFF + ((c.i >> 16) & 1);
    return (uint16_t)(r >> 16);
}

// single-instruction pack of 2 fp32 -> 2 bf16 (low=lo, high=hi), RNE
__device__ inline uint32_t cvtpk_bf16(float lo, float hi) {
    uint32_t r;
    asm("v_cvt_pk_bf16_f32 %0, %1, %2" : "=v"(r) : "v"(lo), "v"(hi));
    return r;
}

// raw v_exp_f32: exp2 without the OCML denormal-range wrapper.
__device__ inline float exp2_raw(float x) { return __builtin_amdgcn_exp2f(x); }

// async global->LDS, 16B per lane; LDS dest must be wave-uniform base (+lane*16 implicit)
__device__ inline void gld_lds16(const uint16_t* g, uint16_t* l) {
    __builtin_amdgcn_global_load_lds(
        (const __attribute__((address_space(1))) void*)g,
        (__attribute__((address_space(3))) void*)l,
        16, 0, 0);
}

// ---------------- prep: fill_x + fill_s + conv(q_w) + conv(kv_w) + conv(proj_w) ----
#define FILLB 4752            // M_PAD*(DIM/8)/256
#define CONVQ_B 288           // DIM*DIM/8/256
#define CONVKV_B 576          // 2*DIM*DIM/8/256
__global__ void prep(const float* __restrict__ t_x, const float* __restrict__ s_x,
                     const float* __restrict__ pos,
                     const float* __restrict__ q_w, const float* __restrict__ kv_w,
                     const float* __restrict__ proj_w,
                     uint16_t* __restrict__ x_pad, uint16_t* __restrict__ s_pad,
                     uint16_t* __restrict__ wq, uint16_t* __restrict__ wkv,
                     uint16_t* __restrict__ wproj) {
    int bx = blockIdx.x, tid = threadIdx.x;
    if (bx < FILLB) {
        int chunk = bx * 256 + tid;
        size_t off = (size_t)chunk * 8;
        s16x8 o;
        if (off < (size_t)M_REAL * DIM) {
            float4 a = *(const float4*)(t_x + off);
            float4 b = *(const float4*)(t_x + off + 4);
            union { s16x8 v; uint32_t u[4]; } p;
            p.u[0] = cvtpk_bf16(a.x, a.y);
            p.u[1] = cvtpk_bf16(a.z, a.w);
            p.u[2] = cvtpk_bf16(b.x, b.y);
            p.u[3] = cvtpk_bf16(b.z, b.w);
            o = p.v;
        } else {
            for (int j = 0; j < 8; j++) o[j] = 0;
        }
        *(s16x8*)(x_pad + off) = o;
    } else if (bx < 2 * FILLB) {
        int chunk = (bx - FILLB) * 256 + tid;
        int i = chunk / (DIM / 8);
        int cc = chunk - i * (DIM / 8);
        int d0 = cc * 8;
        uint16_t* dst = s_pad + (size_t)i * DIM + d0;
        if (i >= M_REAL) {
            s16x8 z; for (int j = 0; j < 8; j++) z[j] = 0;
            *(s16x8*)dst = z;
            return;
        }
        int b = i / NK, rr = i - b * NK;
        int t_i = rr / NSPACE, n_i = rr - t_i * NSPACE;
        const float* src = s_x + ((size_t)(n_i * (BATCH * TFRAMES) + b * TFRAMES + t_i)) * DIM + d0;
        const float* ps = pos + (size_t)rr * DIM + d0;
        float4 a0 = *(const float4*)src;
        float4 a1 = *(const float4*)(src + 4);
        float4 p0 = *(const float4*)ps;
        float4 p1 = *(const float4*)(ps + 4);
        union { s16x8 v; uint32_t u[4]; } o;
        o.u[0] = cvtpk_bf16(a0.x + p0.x, a0.y + p0.y);
        o.u[1] = cvtpk_bf16(a0.z + p0.z, a0.w + p0.w);
        o.u[2] = cvtpk_bf16(a1.x + p1.x, a1.y + p1.y);
        o.u[3] = cvtpk_bf16(a1.z + p1.z, a1.w + p1.w);
        *(s16x8*)dst = o.v;
    } else if (bx < 2 * FILLB + CONVQ_B) {
        int chunk = (bx - 2 * FILLB) * 256 + tid;
        size_t off = (size_t)chunk * 8;
        float4 a = *(const float4*)(q_w + off);
        float4 b = *(const float4*)(q_w + off + 4);
        union { s16x8 v; uint32_t u[4]; } o;
        o.u[0] = cvtpk_bf16(a.x, a.y);
        o.u[1] = cvtpk_bf16(a.z, a.w);
        o.u[2] = cvtpk_bf16(b.x, b.y);
        o.u[3] = cvtpk_bf16(b.z, b.w);
        *(s16x8*)(wq + off) = o.v;
    } else if (bx < 2 * FILLB + CONVQ_B + CONVKV_B) {
        int chunk = (bx - 2 * FILLB - CONVQ_B) * 256 + tid;
        size_t off = (size_t)chunk * 8;
        float4 a = *(const float4*)(kv_w + off);
        float4 b = *(const float4*)(kv_w + off + 4);
        union { s16x8 v; uint32_t u[4]; } o;
        o.u[0] = cvtpk_bf16(a.x, a.y);
        o.u[1] = cvtpk_bf16(a.z, a.w);
        o.u[2] = cvtpk_bf16(b.x, b.y);
        o.u[3] = cvtpk_bf16(b.z, b.w);
        *(s16x8*)(wkv + off) = o.v;
    } else {
        int chunk = (bx - 2 * FILLB - CONVQ_B - CONVKV_B) * 256 + tid;
        size_t off = (size_t)chunk * 8;
        float4 a = *(const float4*)(proj_w + off);
        float4 b = *(const float4*)(proj_w + off + 4);
        union { s16x8 v; uint32_t u[4]; } o;
        o.u[0] = cvtpk_bf16(a.x, a.y);
        o.u[1] = cvtpk_bf16(a.z, a.w);
        o.u[2] = cvtpk_bf16(b.x, b.y);
        o.u[3] = cvtpk_bf16(b.z, b.w);
        *(s16x8*)(wproj + off) = o.v;
    }
}

// ---------------- GEMM (round-2 verified, BK=32 linear): C = A @ W^T + bias ------
// MODE 0: Q -> q_buf scaled; MODE 1: KV -> k_buf + v_buf; MODE 2: proj -> fp32 out
template <int MODE>
__global__ __launch_bounds__(256)
void gemm_bt(const uint16_t* __restrict__ A, const uint16_t* __restrict__ W,
             const float* __restrict__ bias,
             uint16_t* __restrict__ out0, uint16_t* __restrict__ out1,
             float* __restrict__ outf) {
    __shared__ uint16_t As[128 * 32];
    __shared__ uint16_t Bs[128 * 32];
    const int t = threadIdx.x;
    const int lane = t & 63, w = t >> 6;
    const int r16 = lane & 15, quad = lane >> 4;
    const int wm = w >> 1, wn = w & 1;
    const int m0 = blockIdx.y * 128;
    const int n0 = blockIdx.x * 128;

    const int srow = w * 32 + (lane >> 2);
    const int scol = (lane & 3) * 8;
    const uint16_t* Ag = A + (size_t)(m0 + srow) * DIM + scol;
    const uint16_t* Wg = W + (size_t)(n0 + srow) * DIM + scol;
    uint16_t* Asw = &As[w * 32 * 32];
    uint16_t* Bsw = &Bs[w * 32 * 32];

    f32x4 acc[4][4];
    for (int a = 0; a < 4; a++)
        for (int bb = 0; bb < 4; bb++)
            for (int r = 0; r < 4; r++) acc[a][bb][r] = 0.f;

    for (int kk = 0; kk < DIM; kk += 32) {
        gld_lds16(Ag + kk, Asw);
        gld_lds16(Ag + kk + (size_t)16 * DIM, Asw + 16 * 32);
        gld_lds16(Wg + kk, Bsw);
        gld_lds16(Wg + kk + (size_t)16 * DIM, Bsw + 16 * 32);
        __syncthreads();
        s16x8 af[4], bfr[4];
        for (int mt = 0; mt < 4; mt++)
            af[mt] = *(const s16x8*)&As[(wm * 64 + mt * 16 + r16) * 32 + quad * 8];
        for (int nt = 0; nt < 4; nt++)
            bfr[nt] = *(const s16x8*)&Bs[(wn * 64 + nt * 16 + r16) * 32 + quad * 8];
        for (int mt = 0; mt < 4; mt++)
            for (int nt = 0; nt < 4; nt++)
                acc[mt][nt] = __builtin_amdgcn_mfma_f32_16x16x32_bf16(af[mt], bfr[nt], acc[mt][nt], 0, 0, 0);
        __syncthreads();
    }

    for (int mt = 0; mt < 4; mt++)
        for (int nt = 0; nt < 4; nt++) {
            int col = n0 + wn * 64 + nt * 16 + r16;
            float bz = bias[col];
            int rowb = m0 + wm * 64 + mt * 16 + quad * 4;
            for (int r = 0; r < 4; r++) {
                int i = rowb + r;
                if (i >= M_REAL) continue;
                float v = acc[mt][nt][r] + bz;
                if (MODE == 0) {
                    int b = i / NQ, nq = i - b * NQ;
                    int h = col >> 6, d = col & 63;
                    out0[(size_t)(((b * NH + h) * NQ) + nq) * HD + d] = f2bf(v * 0.18033688011112042f);
                } else if (MODE == 1) {
                    int b = i / NK, nk = i - b * NK;
                    if (col < DIM) {
                        int h = col >> 6, d = col & 63;
                        out0[(size_t)(((b * NH + h) * NK) + nk) * HD + d] = f2bf(v);
                    } else {
                        int c2 = col - DIM;
                        int h = c2 >> 6, d = c2 & 63;
                        out1[(size_t)(((b * NH + h) * NK) + nk) * HD + d] = f2bf(v);
                    }
                } else {
                    outf[(size_t)i * DIM + col] = v;
                }
            }
        }
}

// ---------------- V transpose: (b,h,nk,64) -> (b,h,64,VT_LD) ----------------
__global__ __launch_bounds__(256)
void transpose_v(const uint16_t* __restrict__ v, uint16_t* __restrict__ vt) {
    __shared__ uint16_t T[64 * 72];
    int tile = blockIdx.x, bh = blockIdx.y;
    int nk0 = tile * 64;
    const uint16_t* V = v + (size_t)bh * NK * HD;
    uint16_t* VT = vt + (size_t)bh * HD * VT_LD;
    int tid = threadIdx.x;
    int rr = tid >> 3;
    int c8 = (tid & 7) * 8;
    for (int p = 0; p < 2; p++) {
        int lr = p * 32 + rr;
        int nk = nk0 + lr;
        s16x8 val;
        if (nk < NK) val = *(const s16x8*)(V + (size_t)nk * HD + c8);
        else for (int j = 0; j < 8; j++) val[j] = 0;
        for (int j = 0; j < 8; j++)
            T[(c8 + j) * 72 + lr] = (uint16_t)val[j];
    }
    __syncthreads();
    for (int p = 0; p < 2; p++) {
        int d = p * 32 + rr;
        s16x8 o = *(const s16x8*)&T[d * 72 + c8];
        *(s16x8*)(VT + (size_t)d * VT_LD + nk0 + c8) = o;
    }
}

// ---------------- flash attention v8 (verified 96.9us): 128 q/wg, XCD-chunked ----
// Grid flattened to 1248 = 8 XCDs x 156; wgid%8 selects XCD (HW round-robin),
// work = xcd*156 + wgid/8 -> all 13 q-blocks of one (b,h) land on ONE XCD: its
// private L2 serves the shared 400KB K/VT (FETCH 165MB -> 28.6MB measured).
// Round-8 lesson: per-wg fixed work (staging+frag reads+barriers) dominates;
// 128 q/wg is the measured sweet spot (64 q/wg: +12% dur despite +17pt occ).
#define NITER 50
#define FLASH_WG 1248   // 13 * NH * BATCH
__global__ __launch_bounds__(256)
void flash_attn(const uint16_t* __restrict__ q_buf, const uint16_t* __restrict__ k_buf,
                const uint16_t* __restrict__ vt_buf, uint16_t* __restrict__ ao) {
    __shared__ uint16_t Kb[2][32 * 72];
    __shared__ uint16_t Vb[2][64 * 40];
    int wgid = blockIdx.x;
    int work = (wgid & 7) * (FLASH_WG / 8) + (wgid >> 3);
    int qb = work % 13;
    int hb = work / 13;
    int h = hb % NH;
    int b = hb / NH;
    int tid = threadIdx.x;
    int lane = tid & 63, w = tid >> 6;
    int r16 = lane & 15, quad = lane >> 4;
    size_t bh = (size_t)(b * NH + h);
    const uint16_t* Q = q_buf + bh * NQ * HD;
    const uint16_t* K = k_buf + bh * NK * HD;
    const uint16_t* VT = vt_buf + bh * HD * VT_LD;
    int q0 = qb * 128 + w * 32;

    const int kg = tid >> 3;
    const int kc = (tid & 7) * 8;
    const int kslot = ((kg >> 3) << 2) + (kg & 3) + ((kg & 4) ? 16 : 0);
    const int vd = tid >> 2;
    const int vc = (tid & 3) * 8;
    const uint16_t* Kg = K + (size_t)kg * HD + kc;
    const uint16_t* Vg = VT + (size_t)vd * VT_LD + vc;
    uint16_t* Kw = &Kb[0][kslot * 72 + kc];
    uint16_t* Vw = &Vb[0][vd * 40 + vc];
    const int KBSZ = 32 * 72, VBSZ = 64 * 40;

    s16x8 qf[2][2];
    for (int m = 0; m < 2; m++) {
        int qrow = q0 + m * 16 + r16;
        if (qrow < NQ) {
            qf[m][0] = *(const s16x8*)(Q + (size_t)qrow * HD + quad * 8);
            qf[m][1] = *(const s16x8*)(Q + (size_t)qrow * HD + 32 + quad * 8);
        } else {
            for (int j = 0; j < 8; j++) { qf[m][0][j] = 0; qf[m][1][j] = 0; }
        }
    }

    f32x4 z4;
    for (int r = 0; r < 4; r++) z4[r] = 0.f;

    f32x4 oT[2][4];
    f32x4 lsum4[2];
    for (int m = 0; m < 2; m++) {
        for (int dt = 0; dt < 4; dt++)
            for (int r = 0; r < 4; r++) oT[m][dt][r] = 0.f;
        for (int r = 0; r < 4; r++) lsum4[m][r] = 0.f;
    }

    {
        s16x8 kv = *(const s16x8*)Kg;
        s16x8 vv = *(const s16x8*)Vg;
        *(s16x8*)Kw = kv;
        *(s16x8*)Vw = vv;
    }
    __syncthreads();

    for (int it = 0; it < NITER - 1; it++) {
        int kb = it * 32;
        int cur = it & 1, nxt = cur ^ 1;
        s16x8 knv = *(const s16x8*)(Kg + (size_t)(kb + 32) * HD);
        s16x8 vnv = *(const s16x8*)(Vg + kb + 32);

        const uint16_t* Kc = &Kb[cur][0];
        const uint16_t* Vc = &Vb[cur][0];
        s16x8 kfA0 = *(const s16x8*)(Kc + r16 * 72 + quad * 8);
        s16x8 kfA1 = *(const s16x8*)(Kc + r16 * 72 + 32 + quad * 8);
        s16x8 kfB0 = *(const s16x8*)(Kc + (16 + r16) * 72 + quad * 8);
        s16x8 kfB1 = *(const s16x8*)(Kc + (16 + r16) * 72 + 32 + quad * 8);

        s16x8 pf[2];
        #pragma unroll
        for (int m = 0; m < 2; m++) {
            f32x4 sA = __builtin_amdgcn_mfma_f32_16x16x32_bf16(kfA0, qf[m][0], z4, 0, 0, 0);
            sA = __builtin_amdgcn_mfma_f32_16x16x32_bf16(kfA1, qf[m][1], sA, 0, 0, 0);
            f32x4 sB = __builtin_amdgcn_mfma_f32_16x16x32_bf16(kfB0, qf[m][0], z4, 0, 0, 0);
            sB = __builtin_amdgcn_mfma_f32_16x16x32_bf16(kfB1, qf[m][1], sB, 0, 0, 0);
            f32x4 pA, pB;
            #pragma unroll
            for (int r = 0; r < 4; r++) { pA[r] = exp2_raw(sA[r]); pB[r] = exp2_raw(sB[r]); }
            lsum4[m] += pA;
            lsum4[m] += pB;
            union { s16x8 v; uint32_t u[4]; } pk;
            pk.u[0] = cvtpk_bf16(pA[0], pA[1]);
            pk.u[1] = cvtpk_bf16(pA[2], pA[3]);
            pk.u[2] = cvtpk_bf16(pB[0], pB[1]);
            pk.u[3] = cvtpk_bf16(pB[2], pB[3]);
            pf[m] = pk.v;
        }
        #pragma unroll
        for (int dt = 0; dt < 4; dt++) {
            s16x8 vf = *(const s16x8*)(Vc + (dt * 16 + r16) * 40 + quad * 8);
            oT[0][dt] = __builtin_amdgcn_mfma_f32_16x16x32_bf16(vf, pf[0], oT[0][dt], 0, 0, 0);
            oT[1][dt] = __builtin_amdgcn_mfma_f32_16x16x32_bf16(vf, pf[1], oT[1][dt], 0, 0, 0);
        }
        *(s16x8*)(Kw + nxt * KBSZ) = knv;
        *(s16x8*)(Vw + nxt * VBSZ) = vnv;
        __syncthreads();
    }

    {
        const int it = NITER - 1;
        const int kb = it * 32;
        const int cur = it & 1;
        const uint16_t* Kc = &Kb[cur][0];
        const uint16_t* Vc = &Vb[cur][0];
        s16x8 kfA0 = *(const s16x8*)(Kc + r16 * 72 + quad * 8);
        s16x8 kfA1 = *(const s16x8*)(Kc + r16 * 72 + 32 + quad * 8);
        s16x8 kfB0 = *(const s16x8*)(Kc + (16 + r16) * 72 + quad * 8);
        s16x8 kfB1 = *(const s16x8*)(Kc + (16 + r16) * 72 + 32 + quad * 8);

        s16x8 pf[2];
        #pragma unroll
        for (int m = 0; m < 2; m++) {
            f32x4 sA = __builtin_amdgcn_mfma_f32_16x16x32_bf16(kfA0, qf[m][0], z4, 0, 0, 0);
            sA = __builtin_amdgcn_mfma_f32_16x16x32_bf16(kfA1, qf[m][1], sA, 0, 0, 0);
            f32x4 sB = __builtin_amdgcn_mfma_f32_16x16x32_bf16(kfB0, qf[m][0], z4, 0, 0, 0);
            sB = __builtin_amdgcn_mfma_f32_16x16x32_bf16(kfB1, qf[m][1], sB, 0, 0, 0);
            f32x4 pA, pB;
            #pragma unroll
            for (int r = 0; r < 4; r++) {
                pA[r] = (kb + quad * 8 + r < NK)     ? exp2_raw(sA[r]) : 0.f;
                pB[r] = (kb + quad * 8 + 4 + r < NK) ? exp2_raw(sB[r]) : 0.f;
            }
            lsum4[m] += pA;
            lsum4[m] += pB;
            union { s16x8 v; uint32_t u[4]; } pk;
            pk.u[0] = cvtpk_bf16(pA[0], pA[1]);
            pk.u[1] = cvtpk_bf16(pA[2], pA[3]);
            pk.u[2] = cvtpk_bf16(pB[0], pB[1]);
            pk.u[3] = cvtpk_bf16(pB[2], pB[3]);
            pf[m] = pk.v;
        }
        #pragma unroll
        for (int dt = 0; dt < 4; dt++) {
            s16x8 vf = *(const s16x8*)(Vc + (dt * 16 + r16) * 40 + quad * 8);
            oT[0][dt] = __builtin_amdgcn_mfma_f32_16x16x32_bf16(vf, pf[0], oT[0][dt], 0, 0, 0);
            oT[1][dt] = __builtin_amdgcn_mfma_f32_16x16x32_bf16(vf, pf[1], oT[1][dt], 0, 0, 0);
        }
    }

    #pragma unroll
    for (int m = 0; m < 2; m++) {
        float rs = lsum4[m][0] + lsum4[m][1] + lsum4[m][2] + lsum4[m][3];
        rs += __shfl_xor(rs, 16);
        rs += __shfl_xor(rs, 32);
        int q = q0 + m * 16 + r16;
        if (q >= NQ) continue;
        float inv = 1.0f / rs;
        size_t rowoff = (size_t)(b * NQ + q) * DIM + h * HD;
        #pragma unroll
        for (int dt = 0; dt < 4; dt++) {
            union { s16x4 v; uint32_t u[2]; } o;
            o.u[0] = cvtpk_bf16(oT[m][dt][0] * inv, oT[m][dt][1] * inv);
            o.u[1] = cvtpk_bf16(oT[m][dt][2] * inv, oT[m][dt][3] * inv);
            *(s16x4*)(ao + rowoff + dt * 16 + quad * 4) = o.v;
        }
    }
}

// ---------------- launch ----------------
extern "C" void kernel_launch(void* const* d_in, const int* in_sizes, int n_in,
                              void* d_out, int out_size, void* d_ws, size_t ws_size,
                              hipStream_t stream) {
    const float* s_x    = (const float*)d_in[0];
    const float* t_x    = (const float*)d_in[1];
    const float* pos    = (const float*)d_in[2];
    const float* q_w    = (const float*)d_in[3];
    const float* q_b    = (const float*)d_in[4];
    const float* kv_w   = (const float*)d_in[5];
    const float* kv_b   = (const float*)d_in[6];
    const float* proj_w = (const float*)d_in[7];
    const float* proj_b = (const float*)d_in[8];
    float* out = (float*)d_out;

    char* ws = (char*)d_ws;
    size_t off = 0;
    auto carve = [&](size_t bytes) {
        void* p = ws + off;
        off += (bytes + 255) & ~(size_t)255;
        return p;
    };
    uint16_t* x_pad     = (uint16_t*)carve((size_t)M_PAD * DIM * 2);
    uint16_t* s_pad     = (uint16_t*)carve((size_t)M_PAD * DIM * 2);
    uint16_t* q_buf     = (uint16_t*)carve((size_t)BATCH * NH * NQ * HD * 2);
    uint16_t* k_buf     = (uint16_t*)carve((size_t)BATCH * NH * NK * HD * 2);
    uint16_t* vt_buf    = (uint16_t*)carve((size_t)BATCH * NH * HD * VT_LD * 2);
    uint16_t* wq_buf    = (uint16_t*)carve((size_t)DIM * DIM * 2);
    uint16_t* wkv_buf   = (uint16_t*)carve((size_t)2 * DIM * DIM * 2);
    uint16_t* wproj_buf = (uint16_t*)carve((size_t)DIM * DIM * 2);
    if (off > ws_size) return;
    uint16_t* v_buf = x_pad;   // x_pad dead after Q GEMM
    uint16_t* ao    = x_pad;   // v_buf dead after transpose

    const int prep_blocks = 2 * FILLB + 2 * CONVQ_B + CONVKV_B;

    prep<<<prep_blocks, 256, 0, stream>>>(t_x, s_x, pos, q_w, kv_w, proj_w,
                                          x_pad, s_pad, wq_buf, wkv_buf, wproj_buf);

    gemm_bt<0><<<dim3(DIM / 128, M_PAD / 128), 256, 0, stream>>>(x_pad, wq_buf, q_b, q_buf, nullptr, nullptr);
    gemm_bt<1><<<dim3(2 * DIM / 128, M_PAD / 128), 256, 0, stream>>>(s_pad, wkv_buf, kv_b, k_buf, v_buf, nullptr);
    transpose_v<<<dim3(VT_LD / 64, BATCH * NH), 256, 0, stream>>>(v_buf, vt_buf);

    flash_attn<<<FLASH_WG, 256, 0, stream>>>(q_buf, k_buf, vt_buf, ao);

    gemm_bt<2><<<dim3(DIM / 128, M_PAD / 128), 256, 0, stream>>>(ao, wproj_buf, proj_b, nullptr, nullptr, out);
}